// Round 10
// baseline (118.415 us; speedup 1.0000x reference)
//
#include <hip/hip_runtime.h>

typedef float v2f __attribute__((ext_vector_type(2)));
typedef __fp16 h2 __attribute__((ext_vector_type(2)));  // matches cvt_pkrtz/fdot2 builtin types

#define B_ 64
#define T_ 2048
#define D_ 512
#define K_ 8
#define WAVES 4
#define THREADS (WAVES * 64)  // 256
#define LOG2E 1.44269504088896340736f

__device__ __forceinline__ float dev_exp2(float v) {
  return __builtin_amdgcn_exp2f(v);
}

// f16 2-way dot with f32 accumulate (v_dot2_f32_f16), guarded.
__device__ __forceinline__ float fdot2(h2 a, h2 b, float c) {
#if __has_builtin(__builtin_amdgcn_fdot2)
  return __builtin_amdgcn_fdot2(a, b, c, false);
#else
  return c + (float)a.x * (float)b.x + (float)a.y * (float)b.y;
#endif
}

__device__ __forceinline__ h2 pack2(float a, float b) {
  return __builtin_amdgcn_cvt_pkrtz(a, b);
}

// Wave64 all-reduce, 100% VALU via builtins (round-8 proven: compiler-managed
// DPP hazards; raw asm DPP (r4) and self-permlane-swap (r7) both corrupted).
template <int CTRL, int RMASK>
__device__ __forceinline__ float dpp_add(float v) {
  int vi = __builtin_bit_cast(int, v);
  int sh = __builtin_amdgcn_update_dpp(0, vi, CTRL, RMASK, 0xF, true);
  return v + __builtin_bit_cast(float, sh);
}

__device__ __forceinline__ float wave_sum(float v) {
  v = dpp_add<0x121, 0xF>(v);  // row_ror:1
  v = dpp_add<0x122, 0xF>(v);  // row_ror:2
  v = dpp_add<0x124, 0xF>(v);  // row_ror:4
  v = dpp_add<0x128, 0xF>(v);  // row_ror:8  -> row sums
  v = dpp_add<0x142, 0xA>(v);  // row_bcast15 into rows 1,3
  v = dpp_add<0x143, 0xC>(v);  // row_bcast31 into rows 2,3 -> lane63 = total
  return __builtin_bit_cast(float,
      __builtin_amdgcn_readlane(__builtin_bit_cast(int, v), 63));
}

// Kernel 1. Round-9/10 change: OCCUPANCY. All prior variants were stuck at
// 2 waves/SIMD (VGPR ~220 cap AND grid 512 blocks = 2 blocks/CU). Now:
// w stored as packed f16 (32 VGPR instead of 64, dots via v_dot2_f32_f16),
// NCHUNK=16 -> 1024 blocks, launch_bounds(256,3) -> 3 blocks/CU.
// Logit f16 precision: |err| ~5e-4 on logits ~N(0,1) -> negligible.
// acc path stays fp32 (precision-critical).
template <int NCHUNK_T>
__global__ __launch_bounds__(THREADS, 3) void k1_accum(
    const float* __restrict__ x, const float* __restrict__ attn_w,
    const float* __restrict__ attn_b, float* __restrict__ ax_part,
    float* __restrict__ asum_part) {
  constexpr int RPC = T_ / NCHUNK_T;   // rows per chunk
  constexpr int RPW = RPC / WAVES;     // rows per wave
  constexpr int PAIRS_T = RPW / 2;

  const int blk = blockIdx.x;
  const int b = blk / NCHUNK_T;
  const int chunk = blk % NCHUNK_T;
  const int tid = threadIdx.x;
  const int wave = tid >> 6;
  const int lane = tid & 63;
  const int lane4 = lane << 2;

  // packed-f16 weights, pre-scaled by log2e (logits feed only softmax)
  h2 wh[K_][4];
#pragma unroll
  for (int k = 0; k < K_; ++k) {
    const float4 w0 = *reinterpret_cast<const float4*>(attn_w + k * D_ + lane4);
    const float4 w1 = *reinterpret_cast<const float4*>(attn_w + k * D_ + 256 + lane4);
    wh[k][0] = pack2(w0.x * LOG2E, w0.y * LOG2E);
    wh[k][1] = pack2(w0.z * LOG2E, w0.w * LOG2E);
    wh[k][2] = pack2(w1.x * LOG2E, w1.y * LOG2E);
    wh[k][3] = pack2(w1.z * LOG2E, w1.w * LOG2E);
  }
  float bias[K_];
#pragma unroll
  for (int k = 0; k < K_; ++k) bias[k] = attn_b[k] * LOG2E;

  v2f acc2[K_][4];
  float asum[K_];
#pragma unroll
  for (int k = 0; k < K_; ++k) {
    asum[k] = 0.f;
#pragma unroll
    for (int j = 0; j < 4; ++j) acc2[k][j] = (v2f){0.f, 0.f};
  }

  const float* xw = x + ((size_t)b * T_ + (size_t)chunk * RPC +
                         (size_t)wave * RPW) * (size_t)D_;

#define LOADPAIR(P00, P01, P10, P11, pairidx)                                  \
  do {                                                                         \
    const float* rp_ = xw + (size_t)(2 * (pairidx)) * D_;                      \
    P00 = *reinterpret_cast<const float4*>(rp_ + lane4);                       \
    P01 = *reinterpret_cast<const float4*>(rp_ + 256 + lane4);                 \
    P10 = *reinterpret_cast<const float4*>(rp_ + D_ + lane4);                  \
    P11 = *reinterpret_cast<const float4*>(rp_ + D_ + 256 + lane4);            \
  } while (0)

  auto process = [&](const float4& r0lo, const float4& r0hi,
                     const float4& r1lo, const float4& r1hi) {
    const v2f x0[4] = {{r0lo.x, r0lo.y}, {r0lo.z, r0lo.w},
                       {r0hi.x, r0hi.y}, {r0hi.z, r0hi.w}};
    const v2f x1[4] = {{r1lo.x, r1lo.y}, {r1lo.z, r1lo.w},
                       {r1hi.x, r1hi.y}, {r1hi.z, r1hi.w}};
    // f16 copies for the logit dots only
    h2 xh0[4], xh1[4];
#pragma unroll
    for (int j = 0; j < 4; ++j) {
      xh0[j] = pack2(x0[j].x, x0[j].y);
      xh1[j] = pack2(x1[j].x, x1[j].y);
    }
    float p0[K_], p1[K_];
#pragma unroll
    for (int k = 0; k < K_; ++k) {
      float s0 = fdot2(xh0[0], wh[k][0], 0.f);
      float s1 = fdot2(xh1[0], wh[k][0], 0.f);
#pragma unroll
      for (int j = 1; j < 4; ++j) {
        s0 = fdot2(xh0[j], wh[k][j], s0);
        s1 = fdot2(xh1[j], wh[k][j], s1);
      }
      p0[k] = s0;
      p1[k] = s1;
    }
#pragma unroll
    for (int k = 0; k < K_; ++k) {
      p0[k] = wave_sum(p0[k]);
      p1[k] = wave_sum(p1[k]);
    }
    // softmax over K=8 in exp2 domain; no max-subtraction (logits ~ N(0,1)).
    float t0 = 0.f, t1 = 0.f;
#pragma unroll
    for (int k = 0; k < K_; ++k) {
      p0[k] = dev_exp2(p0[k] + bias[k]);
      p1[k] = dev_exp2(p1[k] + bias[k]);
      t0 += p0[k];
      t1 += p1[k];
    }
    const float inv0 = __builtin_amdgcn_rcpf(t0);
    const float inv1 = __builtin_amdgcn_rcpf(t1);
#pragma unroll
    for (int k = 0; k < K_; ++k) {
      const float a0 = p0[k] * inv0;
      const float a1 = p1[k] * inv1;
      asum[k] += a0 + a1;
      const v2f av0 = {a0, a0}, av1 = {a1, a1};
#pragma unroll
      for (int j = 0; j < 4; ++j)
        acc2[k][j] += av0 * x0[j] + av1 * x1[j];
    }
  };

  float4 A00, A01, A10, A11, B00, B01, B10, B11;
  LOADPAIR(A00, A01, A10, A11, 0);
  LOADPAIR(B00, B01, B10, B11, 1);

  for (int p = 0; p < PAIRS_T; p += 2) {
    process(A00, A01, A10, A11);
    const int pa = (p + 2 < PAIRS_T) ? (p + 2) : p;  // clamped refill
    LOADPAIR(A00, A01, A10, A11, pa);
    process(B00, B01, B10, B11);
    const int pb = (p + 3 < PAIRS_T) ? (p + 3) : (p + 1);
    LOADPAIR(B00, B01, B10, B11, pb);
  }
#undef LOADPAIR

  // cross-wave reduction in LDS (sequential rounds -> deterministic)
  __shared__ __align__(16) float lds_ax[K_ * D_];  // 16 KiB
  __shared__ float lds_asum[WAVES][K_];
  if (lane == 0) {
#pragma unroll
    for (int k = 0; k < K_; ++k) lds_asum[wave][k] = asum[k];
  }
  for (int wv = 0; wv < WAVES; ++wv) {
    if (wave == wv) {
#pragma unroll
      for (int k = 0; k < K_; ++k)
#pragma unroll
        for (int j = 0; j < 8; ++j) {
          const float val = (j & 1) ? acc2[k][j >> 1].y : acc2[k][j >> 1].x;
          const int d = (j < 4) ? (lane4 + j) : (256 + lane4 + j - 4);
          if (wv == 0)
            lds_ax[k * D_ + d] = val;
          else
            lds_ax[k * D_ + d] += val;
        }
    }
    __syncthreads();
  }

  float4* outp = reinterpret_cast<float4*>(ax_part + (size_t)blk * (K_ * D_));
  const float4* lp = reinterpret_cast<const float4*>(lds_ax);
#pragma unroll
  for (int i = 0; i < (K_ * D_ / 4) / THREADS; ++i)  // 4 iters
    outp[tid + i * THREADS] = lp[tid + i * THREADS];
  if (tid < K_) {
    float s = 0.f;
#pragma unroll
    for (int wv = 0; wv < WAVES; ++wv) s += lds_asum[wv][tid];
    asum_part[blk * K_ + tid] = s;
  }
}

// Kernel 2: reduce chunk partials, subtract asum*centers, L2-normalize per b.
#define K2_THREADS 1024
template <int NCHUNK_T>
__global__ __launch_bounds__(K2_THREADS) void k2_finalize(
    const float* __restrict__ ax_part, const float* __restrict__ asum_part,
    const float* __restrict__ centers, float* __restrict__ out) {
  const int b = blockIdx.x;
  const int tid = threadIdx.x;
  const int wave = tid >> 6;
  const int lane = tid & 63;

  __shared__ float s_asum[K_];
  if (tid < K_) {
    float s = 0.f;
#pragma unroll
    for (int c = 0; c < NCHUNK_T; ++c)
      s += asum_part[(b * NCHUNK_T + c) * K_ + tid];
    s_asum[tid] = s;
  }
  __syncthreads();

  const int NPT = (K_ * D_) / K2_THREADS;  // 4
  float pooled[NPT];
  float sq = 0.f;
  const float* base = ax_part + (size_t)b * NCHUNK_T * (K_ * D_);
#pragma unroll
  for (int i = 0; i < NPT; ++i) {
    const int idx = tid + i * K2_THREADS;
    float v = 0.f;
#pragma unroll
    for (int c = 0; c < NCHUNK_T; ++c) v += base[(size_t)c * (K_ * D_) + idx];
    const int k = idx >> 9;  // idx / D_
    v -= s_asum[k] * centers[idx];
    pooled[i] = v;
    sq = fmaf(v, v, sq);
  }

#pragma unroll
  for (int m = 32; m; m >>= 1) sq += __shfl_xor(sq, m);
  __shared__ float s_sq[K2_THREADS / 64];
  if (lane == 0) s_sq[wave] = sq;
  __syncthreads();
  float tot = 0.f;
#pragma unroll
  for (int wv = 0; wv < K2_THREADS / 64; ++wv) tot += s_sq[wv];
  const float invn = 1.0f / fmaxf(__builtin_sqrtf(tot), 1e-12f);

#pragma unroll
  for (int i = 0; i < NPT; ++i)
    out[(size_t)b * (K_ * D_) + tid + i * K2_THREADS] = pooled[i] * invn;
}

extern "C" void kernel_launch(void* const* d_in, const int* in_sizes, int n_in,
                              void* d_out, int out_size, void* d_ws, size_t ws_size,
                              hipStream_t stream) {
  (void)in_sizes; (void)n_in; (void)out_size;
  const float* x = (const float*)d_in[0];
  const float* centers = (const float*)d_in[1];
  const float* attn_w = (const float*)d_in[2];
  const float* attn_b = (const float*)d_in[3];
  float* out = (float*)d_out;
  float* ax_part = (float*)d_ws;

  const size_t need16 =
      (size_t)B_ * 16 * (K_ * D_) * 4 + (size_t)B_ * 16 * K_ * 4;
  if (ws_size >= need16) {
    float* asum_part = ax_part + (size_t)B_ * 16 * K_ * D_;
    k1_accum<16><<<B_ * 16, THREADS, 0, stream>>>(x, attn_w, attn_b, ax_part,
                                                  asum_part);
    k2_finalize<16><<<B_, K2_THREADS, 0, stream>>>(ax_part, asum_part, centers,
                                                   out);
  } else {
    float* asum_part = ax_part + (size_t)B_ * 8 * K_ * D_;
    k1_accum<8><<<B_ * 8, THREADS, 0, stream>>>(x, attn_w, attn_b, ax_part,
                                                asum_part);
    k2_finalize<8><<<B_, K2_THREADS, 0, stream>>>(ax_part, asum_part, centers,
                                                  out);
  }
}

// Round 11
// 70.663 us; speedup vs baseline: 1.6758x; 1.6758x over previous
//
#include <hip/hip_runtime.h>

typedef float v2f __attribute__((ext_vector_type(2)));
typedef __fp16 h2 __attribute__((ext_vector_type(2)));
typedef __fp16 h8 __attribute__((ext_vector_type(8)));

#define B_ 64
#define T_ 2048
#define D_ 512
#define K_ 8
#define THREADS 256
#define TILE_R 32
#define XPITCH 520   // f16 pitch: 512 + 8 pad -> row stride 1040B, 2-way-free banks
#define LGPITCH 10   // f32 pitch for logits table (conflict-free writes)
#define APITCH 12    // f32 pitch for a-table (16B-aligned rows)
#define LOG2E 1.44269504088896340736f

__device__ __forceinline__ float dev_exp2(float v) { return __builtin_amdgcn_exp2f(v); }
__device__ __forceinline__ h2 pack2(float a, float b) { return __builtin_amdgcn_cvt_pkrtz(a, b); }

// f16 2-wide dot, f32 accumulate (v_dot2_f32_f16; compiled fine in round 10)
__device__ __forceinline__ float fdot2(h2 a, h2 b, float c) {
#if __has_builtin(__builtin_amdgcn_fdot2)
  return __builtin_amdgcn_fdot2(a, b, c, false);
#else
  return c + (float)a[0] * (float)b[0] + (float)a[1] * (float)b[1];
#endif
}

// Kernel 1, restructured (round 11): no cross-lane reduce anywhere.
//   stage:  32-row x-tile -> LDS f16 (coalesced 1KB/instr global loads)
//   pass1:  lane = (row, k) owns a full 512-deep dot via v_dot2_f32_f16
//           (4 indep partial chains); logits -> small LDS table
//   softmax: lane-per-row, lane-local (K=8), exp2 domain (W,b pre-scaled)
//   pass2:  lane owns d-pair; a broadcast-read from LDS; 8 v_pk_fma_f32/row
// VALU ~6x less than the allreduce structure; VGPR ~90 (no launch_bounds
// force -- round 10's force caused spills); LDS 44KB -> 3 blocks/CU.
template <int NCHUNK_T>
__global__ __launch_bounds__(THREADS) void k1_accum(
    const float* __restrict__ x, const float* __restrict__ attn_w,
    const float* __restrict__ attn_b, float* __restrict__ ax_part,
    float* __restrict__ asum_part) {
  constexpr int RPC = T_ / NCHUNK_T;   // rows per chunk
  constexpr int TILES = RPC / TILE_R;  // tiles per block

  const int blk = blockIdx.x;
  const int b = blk / NCHUNK_T;
  const int chunk = blk % NCHUNK_T;
  const int tid = threadIdx.x;
  const int wave = tid >> 6;
  const int lane = tid & 63;

  __shared__ __align__(16) __fp16 xt[TILE_R * XPITCH];  // 33.3 KB
  __shared__ __align__(16) __fp16 wt[K_ * XPITCH];      // 8.3 KB
  __shared__ float lg[TILE_R * LGPITCH];                // 1.3 KB
  __shared__ __align__(16) float at[TILE_R * APITCH];   // 1.5 KB

  // ---- stage W once (pre-scaled by log2e; logits feed only softmax)
  {
    const int k = tid >> 5;
    const int d0 = (tid & 31) * 16;
    const float4* wp = (const float4*)(attn_w + k * D_ + d0);
    const float4 f0 = wp[0], f1 = wp[1], f2 = wp[2], f3 = wp[3];
    h2* wdst = (h2*)(wt + k * XPITCH + d0);
    wdst[0] = pack2(f0.x * LOG2E, f0.y * LOG2E);
    wdst[1] = pack2(f0.z * LOG2E, f0.w * LOG2E);
    wdst[2] = pack2(f1.x * LOG2E, f1.y * LOG2E);
    wdst[3] = pack2(f1.z * LOG2E, f1.w * LOG2E);
    wdst[4] = pack2(f2.x * LOG2E, f2.y * LOG2E);
    wdst[5] = pack2(f2.z * LOG2E, f2.w * LOG2E);
    wdst[6] = pack2(f3.x * LOG2E, f3.y * LOG2E);
    wdst[7] = pack2(f3.z * LOG2E, f3.w * LOG2E);
  }

  const int r1 = lane & 31;                 // pass1 row
  const int myk = wave * 2 + (lane >> 5);   // pass1 k (8 slots = 4 waves x 2 halves)
  const float mybias = attn_b[myk] * LOG2E;
  const int d0p2 = wave * 128 + lane * 2;   // pass2 d-pair ownership

  v2f acc[K_];
#pragma unroll
  for (int k = 0; k < K_; ++k) acc[k] = (v2f){0.f, 0.f};
  v2f asum01 = {0.f, 0.f}, asum23 = {0.f, 0.f}, asum45 = {0.f, 0.f}, asum67 = {0.f, 0.f};

  const float* xbase = x + ((size_t)b * T_ + (size_t)chunk * RPC) * (size_t)D_;

  for (int t = 0; t < TILES; ++t) {
    __syncthreads();  // xt/at free from previous tile's pass2
    // ---- stage tile (16384 f32): instr i covers a contiguous 4KB block-wide
    {
      const float* src = xbase + (size_t)t * TILE_R * D_;
#pragma unroll
      for (int i = 0; i < 16; ++i) {
        const int g = i * 1024 + tid * 4;
        const float4 v = *(const float4*)(src + g);
        const int rr = g >> 9;
        const int dd = g & 511;
        h2* dst = (h2*)(xt + rr * XPITCH + dd);
        dst[0] = pack2(v.x, v.y);
        dst[1] = pack2(v.z, v.w);
      }
    }
    __syncthreads();
    // ---- pass1: full 512-deep dot per (row, k) lane; 4 indep chains
    {
      float s0 = 0.f, s1 = 0.f, s2 = 0.f, s3 = 0.f;
      const h8* xr = (const h8*)(xt + r1 * XPITCH);
      const h8* wr = (const h8*)(wt + myk * XPITCH);
#pragma unroll 8
      for (int c = 0; c < 64; ++c) {
        const h8 xv = xr[c];
        const h8 wv = wr[c];
        s0 = fdot2((h2){xv[0], xv[1]}, (h2){wv[0], wv[1]}, s0);
        s1 = fdot2((h2){xv[2], xv[3]}, (h2){wv[2], wv[3]}, s1);
        s2 = fdot2((h2){xv[4], xv[5]}, (h2){wv[4], wv[5]}, s2);
        s3 = fdot2((h2){xv[6], xv[7]}, (h2){wv[6], wv[7]}, s3);
      }
      lg[r1 * LGPITCH + myk] = (s0 + s1) + (s2 + s3) + mybias;
    }
    __syncthreads();
    // ---- softmax: lane-per-row, lane-local (exp2 domain, no max-sub:
    //      logits ~ N(0,1), fp32-safe; ratio identical)
    if (wave == 0 && lane < 32) {
      const float* lr = lg + lane * LGPITCH;
      float e0 = dev_exp2(lr[0]), e1 = dev_exp2(lr[1]);
      float e2 = dev_exp2(lr[2]), e3 = dev_exp2(lr[3]);
      float e4 = dev_exp2(lr[4]), e5 = dev_exp2(lr[5]);
      float e6 = dev_exp2(lr[6]), e7 = dev_exp2(lr[7]);
      const float tot = ((e0 + e1) + (e2 + e3)) + ((e4 + e5) + (e6 + e7));
      const float inv = __builtin_amdgcn_rcpf(tot);
      float4* adst = (float4*)(at + lane * APITCH);
      adst[0] = (float4){e0 * inv, e1 * inv, e2 * inv, e3 * inv};
      adst[1] = (float4){e4 * inv, e5 * inv, e6 * inv, e7 * inv};
    }
    __syncthreads();
    // ---- pass2: acc[k] += a[r][k] * x[r][d-pair]; a reads are broadcasts
#pragma unroll 4
    for (int rr = 0; rr < TILE_R; ++rr) {
      const float4 alo = *(const float4*)(at + rr * APITCH);
      const float4 ahi = *(const float4*)(at + rr * APITCH + 4);
      const h2 xp = *(const h2*)(xt + rr * XPITCH + d0p2);
      const v2f xv = {(float)xp[0], (float)xp[1]};
      acc[0] += (v2f){alo.x, alo.x} * xv;
      acc[1] += (v2f){alo.y, alo.y} * xv;
      acc[2] += (v2f){alo.z, alo.z} * xv;
      acc[3] += (v2f){alo.w, alo.w} * xv;
      acc[4] += (v2f){ahi.x, ahi.x} * xv;
      acc[5] += (v2f){ahi.y, ahi.y} * xv;
      acc[6] += (v2f){ahi.z, ahi.z} * xv;
      acc[7] += (v2f){ahi.w, ahi.w} * xv;
      if (wave == 0) {  // wave-uniform: asum tracked once (identical in all lanes)
        asum01 += (v2f){alo.x, alo.y};
        asum23 += (v2f){alo.z, alo.w};
        asum45 += (v2f){ahi.x, ahi.y};
        asum67 += (v2f){ahi.z, ahi.w};
      }
    }
  }

  // ---- write per-chunk partials (coalesced dwordx2)
  float* outp = ax_part + (size_t)blk * (K_ * D_);
#pragma unroll
  for (int k = 0; k < K_; ++k) *(v2f*)(outp + k * D_ + d0p2) = acc[k];
  if (tid == 0) {
    float* ap = asum_part + blk * K_;
    ap[0] = asum01.x; ap[1] = asum01.y; ap[2] = asum23.x; ap[3] = asum23.y;
    ap[4] = asum45.x; ap[5] = asum45.y; ap[6] = asum67.x; ap[7] = asum67.y;
  }
}

// k2a: 4 blocks per batch -> reduce chunks, subtract asum*centers, partial sq
template <int NCHUNK_T>
__global__ __launch_bounds__(256) void k2a(
    const float* __restrict__ ax_part, const float* __restrict__ asum_part,
    const float* __restrict__ centers, float* __restrict__ pbuf,
    float* __restrict__ sqpart) {
  const int b = blockIdx.x >> 2;
  const int q = blockIdx.x & 3;
  const int tid = threadIdx.x;
  __shared__ float s_as[K_];
  __shared__ float s_sq[4];
  if (tid < K_) {
    float s = 0.f;
    for (int c = 0; c < NCHUNK_T; ++c) s += asum_part[(b * NCHUNK_T + c) * K_ + tid];
    s_as[tid] = s;
  }
  __syncthreads();
  const int idx = q * 1024 + tid * 4;
  float4 s = {0.f, 0.f, 0.f, 0.f};
  const float* base = ax_part + (size_t)b * NCHUNK_T * (K_ * D_) + idx;
  for (int c = 0; c < NCHUNK_T; ++c) {
    const float4 v = *(const float4*)(base + (size_t)c * (K_ * D_));
    s.x += v.x; s.y += v.y; s.z += v.z; s.w += v.w;
  }
  const int k = idx >> 9;
  const float a = s_as[k];
  const float4 cv = *(const float4*)(centers + idx);
  float4 p;
  p.x = s.x - a * cv.x; p.y = s.y - a * cv.y;
  p.z = s.z - a * cv.z; p.w = s.w - a * cv.w;
  *(float4*)(pbuf + (size_t)b * (K_ * D_) + idx) = p;
  float sq = p.x * p.x + p.y * p.y + p.z * p.z + p.w * p.w;
#pragma unroll
  for (int m = 32; m; m >>= 1) sq += __shfl_xor(sq, m);
  if ((tid & 63) == 0) s_sq[tid >> 6] = sq;
  __syncthreads();
  if (tid == 0) sqpart[blockIdx.x] = (s_sq[0] + s_sq[1]) + (s_sq[2] + s_sq[3]);
}

// k2b: normalize (pbuf is L3-hot)
__global__ __launch_bounds__(1024) void k2b(const float* __restrict__ pbuf,
                                            const float* __restrict__ sqpart,
                                            float* __restrict__ out) {
  const int b = blockIdx.x;
  const float tot =
      (sqpart[b * 4] + sqpart[b * 4 + 1]) + (sqpart[b * 4 + 2] + sqpart[b * 4 + 3]);
  const float invn = 1.0f / fmaxf(__builtin_sqrtf(tot), 1e-12f);
  const int idx = threadIdx.x * 4;
  const float4 p = *(const float4*)(pbuf + (size_t)b * (K_ * D_) + idx);
  *(float4*)(out + (size_t)b * (K_ * D_) + idx) =
      (float4){p.x * invn, p.y * invn, p.z * invn, p.w * invn};
}

// legacy single-kernel finalize (smallest-workspace fallback, round-8 proven)
template <int NCHUNK_T>
__global__ __launch_bounds__(1024) void k2_old(
    const float* __restrict__ ax_part, const float* __restrict__ asum_part,
    const float* __restrict__ centers, float* __restrict__ out) {
  const int b = blockIdx.x;
  const int tid = threadIdx.x;
  const int wave = tid >> 6;
  const int lane = tid & 63;
  __shared__ float s_asum[K_];
  __shared__ float s_sq[16];
  if (tid < K_) {
    float s = 0.f;
    for (int c = 0; c < NCHUNK_T; ++c) s += asum_part[(b * NCHUNK_T + c) * K_ + tid];
    s_asum[tid] = s;
  }
  __syncthreads();
  const int NPT = (K_ * D_) / 1024;  // 4
  float pooled[NPT];
  float sq = 0.f;
  const float* base = ax_part + (size_t)b * NCHUNK_T * (K_ * D_);
#pragma unroll
  for (int i = 0; i < NPT; ++i) {
    const int idx = tid + i * 1024;
    float v = 0.f;
    for (int c = 0; c < NCHUNK_T; ++c) v += base[(size_t)c * (K_ * D_) + idx];
    v -= s_asum[idx >> 9] * centers[idx];
    pooled[i] = v;
    sq = fmaf(v, v, sq);
  }
#pragma unroll
  for (int m = 32; m; m >>= 1) sq += __shfl_xor(sq, m);
  if (lane == 0) s_sq[wave] = sq;
  __syncthreads();
  float tot = 0.f;
#pragma unroll
  for (int wv = 0; wv < 16; ++wv) tot += s_sq[wv];
  const float invn = 1.0f / fmaxf(__builtin_sqrtf(tot), 1e-12f);
#pragma unroll
  for (int i = 0; i < NPT; ++i)
    out[(size_t)b * (K_ * D_) + tid + i * 1024] = pooled[i] * invn;
}

extern "C" void kernel_launch(void* const* d_in, const int* in_sizes, int n_in,
                              void* d_out, int out_size, void* d_ws, size_t ws_size,
                              hipStream_t stream) {
  (void)in_sizes; (void)n_in; (void)out_size;
  const float* x = (const float*)d_in[0];
  const float* centers = (const float*)d_in[1];
  const float* attn_w = (const float*)d_in[2];
  const float* attn_b = (const float*)d_in[3];
  float* out = (float*)d_out;

  const size_t KD = (size_t)K_ * D_;
  // tier sizes: ax + asum + pbuf + sqpart
  const size_t need16 = (size_t)B_ * 16 * KD * 4 + (size_t)B_ * 16 * K_ * 4 +
                        (size_t)B_ * KD * 4 + (size_t)B_ * 4 * 4;
  const size_t need8 = (size_t)B_ * 8 * KD * 4 + (size_t)B_ * 8 * K_ * 4 +
                       (size_t)B_ * KD * 4 + (size_t)B_ * 4 * 4;

  if (ws_size >= need16) {
    float* ax = (float*)d_ws;
    float* as = ax + (size_t)B_ * 16 * KD;
    float* pb = as + (size_t)B_ * 16 * K_;
    float* sp = pb + (size_t)B_ * KD;
    k1_accum<16><<<B_ * 16, THREADS, 0, stream>>>(x, attn_w, attn_b, ax, as);
    k2a<16><<<B_ * 4, 256, 0, stream>>>(ax, as, centers, pb, sp);
    k2b<<<B_, 1024, 0, stream>>>(pb, sp, out);
  } else if (ws_size >= need8) {
    float* ax = (float*)d_ws;
    float* as = ax + (size_t)B_ * 8 * KD;
    float* pb = as + (size_t)B_ * 8 * K_;
    float* sp = pb + (size_t)B_ * KD;
    k1_accum<8><<<B_ * 8, THREADS, 0, stream>>>(x, attn_w, attn_b, ax, as);
    k2a<8><<<B_ * 4, 256, 0, stream>>>(ax, as, centers, pb, sp);
    k2b<<<B_, 1024, 0, stream>>>(pb, sp, out);
  } else {
    float* ax = (float*)d_ws;
    float* as = ax + (size_t)B_ * 8 * KD;
    k1_accum<8><<<B_ * 8, THREADS, 0, stream>>>(x, attn_w, attn_b, ax, as);
    k2_old<8><<<B_, 1024, 0, stream>>>(ax, as, centers, out);
  }
}